// Round 17
// baseline (123.473 us; speedup 1.0000x reference)
//
#include <hip/hip_runtime.h>

// CrumbReconstructor R19: R18 (4-wave quarter-scan, fine-burst overlap —
// confirmed: 65.3 -> 58.6us) with TPK 4->6: same 576 ds_reads/block now
// serve 384 keys -> DS/CU 35 -> 23.5us. VALU (~30-37us total, fixed) is
// now the dominant rail; exposed DS shrinks by 1/3.
//
// R18 post-mortem: measured 58.6 ~ VALU(37) + 0.6*DS(35) -> overlap real,
// 60% of DS still exposed. VGPR=40 w/o spill + clean perf => gfx950 unified
// file: v_fma sources AGPRs directly, k[][] parks in AGPRs for free ->
// higher TPK is register-viable. launch_bounds(256,3): 170-reg combined cap
// (k[6][8]=48 AGPR + 36 window + ~30 misc fits).
//
// Geometry: BLOCK=256 (4 waves x QROW=64 rows), 384 keys/block, grid=2091
// (8.17 blocks/CU, 10% quantization vs R18's 6% — costed in prediction).
// Publish: separate [4][384] u64 (12 KB; LDS 21.25 KB, 3 blocks/CU OK).
// Finalize: 6 key-groups, w0:{0,4} w1:{1,5} w2:{2} w3:{3}, compile-time T.
//
// Exactness (absmax must stay 0.0): DIST chain verbatim (mul, 7x fmaf,
// fmaf(dot,-2,knorm), +rn); within-quarter strict < keeps FIRST group of
// that quarter's min; u64 pack (orderedbits(dist)<<32 | gbase) min over 4
// quarters -> smallest distance, tie -> smallest gbase = earliest index;
// resolve recomputes the winning group's 4 distances from global (L1-hot)
// with the identical op tree, takes FIRST d == best -> reference argmin.

#define LBLK 8          // memblock length
#define NROW 256        // codebook rows
#define QROW 64         // rows per wave (quarter of the row space)
#define BLOCK 256       // 4 waves per block
#define TPK 6           // key-groups per block (64 keys each)
#define WIN 4           // rows per window / argmin group
#define KPB (TPK * 64)  // keys per block = 384

__device__ __forceinline__ unsigned long long packdi(float d, int g) {
    unsigned int b  = __float_as_uint(d);
    unsigned int ob = (b >> 31) ? ~b : (b | 0x80000000u);   // total order
    return ((unsigned long long)ob << 32) | (unsigned int)g;
}

__global__ __launch_bounds__(BLOCK, 3) void crumb_kernel(
    const float* __restrict__ x,
    const float* __restrict__ mem,
    float* __restrict__ out,
    int nblocks)
{
    __shared__ __align__(16) float s_mem[NROW * LBLK];   // 8 KB
    __shared__ __align__(16) float s_norm[NROW];         // 1 KB
    __shared__ unsigned long long s_pub[4 * KPB];        // 12 KB

    const int tid  = threadIdx.x;
    const int lane = tid & 63;
    const int wid  = tid >> 6;          // wave w scans rows [w*64, w*64+64)

    // --- stage codebook: 1 row per thread, coalesced ---
    {
        const float4* g = (const float4*)mem;
        float4 a = g[tid * 2 + 0];
        float4 b = g[tid * 2 + 1];
        ((float4*)s_mem)[tid * 2 + 0] = a;
        ((float4*)s_mem)[tid * 2 + 1] = b;
        float q0 = a.x * a.x, q1 = a.y * a.y, q2 = a.z * a.z, q3 = a.w * a.w;
        float q4 = b.x * b.x, q5 = b.y * b.y, q6 = b.z * b.z, q7 = b.w * b.w;
        s_norm[tid] = ((q0 + q1) + (q2 + q3)) + ((q4 + q5) + (q6 + q7));
    }
    __syncthreads();

    // --- load the block's 384 keys (all 4 waves load the same keys) ---
    float k[TPK][LBLK];
    float knorm[TPK];

    #pragma unroll
    for (int t = 0; t < TPK; ++t) {
        long b0 = (long)blockIdx.x * KPB + t * 64 + lane;
        long kbt = (b0 < (long)nblocks) ? b0 : 0;
        const float4* g = (const float4*)(x + kbt * LBLK);
        float4 a = g[0], b = g[1];
        k[t][0] = a.x; k[t][1] = a.y; k[t][2] = a.z; k[t][3] = a.w;
        k[t][4] = b.x; k[t][5] = b.y; k[t][6] = b.z; k[t][7] = b.w;
        float q0 = a.x * a.x, q1 = a.y * a.y, q2 = a.z * a.z, q3 = a.w * a.w;
        float q4 = b.x * b.x, q5 = b.y * b.y, q6 = b.z * b.z, q7 = b.w * b.w;
        knorm[t] = ((q0 + q1) + (q2 + q3)) + ((q4 + q5) + (q6 + q7));
    }

    float best[TPK];
    int   gbs[TPK];
    const int rbase = wid * QROW;
    #pragma unroll
    for (int t = 0; t < TPK; ++t) { best[t] = 3.4e38f; gbs[t] = rbase; }

    const float4* sm4 = (const float4*)s_mem;

    // the exact reference distance chain (bit-identical everywhere)
#define DIST(T, RA, RB, RN, DST)                                        \
    {                                                                   \
        float dot = k[(T)][0] * (RA).x;                                 \
        dot = fmaf(k[(T)][1], (RA).y, dot);                             \
        dot = fmaf(k[(T)][2], (RA).z, dot);                             \
        dot = fmaf(k[(T)][3], (RA).w, dot);                             \
        dot = fmaf(k[(T)][4], (RB).x, dot);                             \
        dot = fmaf(k[(T)][5], (RB).y, dot);                             \
        dot = fmaf(k[(T)][6], (RB).z, dot);                             \
        dot = fmaf(k[(T)][7], (RB).w, dot);                             \
        (DST) = fmaf(dot, -2.0f, knorm[(T)]) + (RN);                    \
    }

    // --- scan this wave's 64 rows: 16 windows of 4 (proven body) ---
    #pragma unroll 1
    for (int w = 0; w < QROW; w += WIN) {
        const int r = rbase + w;
        float4 A0 = sm4[(r + 0) * 2 + 0], B0 = sm4[(r + 0) * 2 + 1];
        float4 A1 = sm4[(r + 1) * 2 + 0], B1 = sm4[(r + 1) * 2 + 1];
        float4 A2 = sm4[(r + 2) * 2 + 0], B2 = sm4[(r + 2) * 2 + 1];
        float4 A3 = sm4[(r + 3) * 2 + 0], B3 = sm4[(r + 3) * 2 + 1];
        float4 N  = *(const float4*)&s_norm[r];

        #pragma unroll
        for (int t = 0; t < TPK; ++t) {
            float d0, d1, d2, d3;
            DIST(t, A0, B0, N.x, d0);
            DIST(t, A1, B1, N.y, d1);
            DIST(t, A2, B2, N.z, d2);
            DIST(t, A3, B3, N.w, d3);
            // group min (order-independent value; all inputs finite)
            float gm = fminf(fminf(d0, d1), fminf(d2, d3));
            // strict < : FIRST group attaining this quarter's min wins
            if (gm < best[t]) { best[t] = gm; gbs[t] = r; }
        }
    }

    // --- publish: per-wave per-key packed (dist, groupbase) ---
    #pragma unroll
    for (int t = 0; t < TPK; ++t)
        s_pub[wid * KPB + t * 64 + lane] = packdi(best[t], gbs[t]);
    __syncthreads();

    // --- finalize: u64-min over 4 quarters, resolve from global, store ---
#define FINALIZE(T)                                                     \
    {                                                                   \
        long b0 = (long)blockIdx.x * KPB + (T) * 64 + lane;             \
        if (b0 < (long)nblocks) {                                       \
            const int key = (T) * 64 + lane;                            \
            unsigned long long m0 = s_pub[0 * KPB + key];               \
            unsigned long long m1 = s_pub[1 * KPB + key];               \
            unsigned long long m2 = s_pub[2 * KPB + key];               \
            unsigned long long m3 = s_pub[3 * KPB + key];               \
            unsigned long long winv = m0 < m1 ? m0 : m1;                \
            winv = winv < m2 ? winv : m2;                               \
            winv = winv < m3 ? winv : m3;                               \
            unsigned int ob = (unsigned int)(winv >> 32);               \
            unsigned int bb = (ob & 0x80000000u) ? (ob ^ 0x80000000u)   \
                                                 : ~ob;                 \
            float fb = __uint_as_float(bb);                             \
            int   gb = (int)(winv & 0xffffffffu);                       \
            float4 wa = ((const float4*)(mem + (long)gb * LBLK))[0];    \
            float4 wb = ((const float4*)(mem + (long)gb * LBLK))[1];    \
            bool found = false;                                         \
            _Pragma("unroll")                                           \
            for (int j = 0; j < WIN; ++j) {                             \
                const float4* g =                                       \
                    (const float4*)(mem + (long)(gb + j) * LBLK);       \
                float4 a = g[0], b = g[1];                              \
                float q0 = a.x * a.x, q1 = a.y * a.y;                   \
                float q2 = a.z * a.z, q3 = a.w * a.w;                   \
                float q4 = b.x * b.x, q5 = b.y * b.y;                   \
                float q6 = b.z * b.z, q7 = b.w * b.w;                   \
                float nn = ((q0 + q1) + (q2 + q3))                      \
                         + ((q4 + q5) + (q6 + q7));                     \
                float d;                                                \
                DIST((T), a, b, nn, d);                                 \
                bool hit = (d == fb) && !found;                         \
                if (hit) { wa = a; wb = b; }                            \
                found = found || (d == fb);                             \
            }                                                           \
            float4* o = (float4*)(out + b0 * LBLK);                     \
            o[0] = wa;                                                  \
            o[1] = wb;                                                  \
        }                                                               \
    }

    if      (wid == 0) { FINALIZE(0) FINALIZE(4) }
    else if (wid == 1) { FINALIZE(1) FINALIZE(5) }
    else if (wid == 2) { FINALIZE(2) }
    else               { FINALIZE(3) }
#undef FINALIZE
#undef DIST
}

extern "C" void kernel_launch(void* const* d_in, const int* in_sizes, int n_in,
                              void* d_out, int out_size, void* d_ws, size_t ws_size,
                              hipStream_t stream) {
    const float* x   = (const float*)d_in[0];
    const float* mem = (const float*)d_in[1];
    float* out = (float*)d_out;

    int n = in_sizes[0];            // total x elements
    int nblocks = n / LBLK;         // key-blocks (802816 for std shape)
    int grid = (nblocks + KPB - 1) / KPB;   // 2091 for std shape

    hipLaunchKernelGGL(crumb_kernel, dim3(grid), dim3(BLOCK), 0, stream,
                       x, mem, out, nblocks);
}

// Round 18
// 121.502 us; speedup vs baseline: 1.0162x; 1.0162x over previous
//
#include <hip/hip_runtime.h>

// CrumbReconstructor R20: R18 (58.6us champion) with HALF of each window's
// rows sourced from global/L1 instead of LDS — engages the idle VMEM pipe.
//
// R19 post-mortem: TPK axis closed. DS/CU 35->23.5us bought nothing because
// it cost residency (occ 44->29.5%); R18's overlap quality rides on TLP.
// Remaining exposed DS (~25us at R18's point) needs a THIRD pipE:
// VMEM is idle all scan, codebook is 8KB = L1-resident.
//
// Change vs R18 (only this): rows 0-1 of each 4-row window from s_mem (DS),
// rows 2-3 from mem via vector global_load (L1-hot). Same bytes -> same
// distances, bit-exact. DS rows/block 512->256 (plus 64 norm reads);
// vmcnt and lgkmcnt are SEPARATE counters so the two pipes don't serialize.
// TRAP AVOIDED: a provably-uniform address would scalarize to s_load (SMEM
// shares lgkmcnt with DS = R4's disaster). The base pointer is laundered
// through asm "+v" so the compiler must emit global_load_dwordx4.
//
// Exactness (absmax must stay 0.0): DIST chain verbatim (mul, 7x fmaf,
// fmaf(dot,-2,knorm), +rn); within-quarter strict < keeps FIRST group;
// u64 pack (orderedbits<<32|gbase) min over quarters -> smallest distance,
// tie -> smallest gbase = earliest index; resolve recomputes winning group
// from global with the identical op tree, takes FIRST d == best.

#define LBLK 8          // memblock length
#define NROW 256        // codebook rows
#define QROW 64         // rows per wave (quarter of the row space)
#define BLOCK 256       // 4 waves per block
#define TPK 4           // key-groups per thread; block covers 256 keys
#define WIN 4           // rows per window / argmin group

__device__ __forceinline__ unsigned long long packdi(float d, int g) {
    unsigned int b  = __float_as_uint(d);
    unsigned int ob = (b >> 31) ? ~b : (b | 0x80000000u);   // total order
    return ((unsigned long long)ob << 32) | (unsigned int)g;
}

__global__ __launch_bounds__(BLOCK, 4) void crumb_kernel(
    const float* __restrict__ x,
    const float* __restrict__ mem,
    float* __restrict__ out,
    int nblocks)
{
    __shared__ __align__(16) float s_mem[NROW * LBLK];   // 8 KB; publish alias
    __shared__ __align__(16) float s_norm[NROW];         // 1 KB

    const int tid  = threadIdx.x;
    const int lane = tid & 63;
    const int wid  = tid >> 6;          // wave w scans rows [w*64, w*64+64)

    // --- stage codebook: 1 row per thread, coalesced ---
    {
        const float4* g = (const float4*)mem;
        float4 a = g[tid * 2 + 0];
        float4 b = g[tid * 2 + 1];
        ((float4*)s_mem)[tid * 2 + 0] = a;
        ((float4*)s_mem)[tid * 2 + 1] = b;
        float q0 = a.x * a.x, q1 = a.y * a.y, q2 = a.z * a.z, q3 = a.w * a.w;
        float q4 = b.x * b.x, q5 = b.y * b.y, q6 = b.z * b.z, q7 = b.w * b.w;
        s_norm[tid] = ((q0 + q1) + (q2 + q3)) + ((q4 + q5) + (q6 + q7));
    }
    __syncthreads();

    // --- load the block's 256 keys (all 4 waves load the same keys) ---
    float k[TPK][LBLK];
    float knorm[TPK];

    #pragma unroll
    for (int t = 0; t < TPK; ++t) {
        long b0 = (long)blockIdx.x * 256 + t * 64 + lane;
        long kbt = (b0 < (long)nblocks) ? b0 : 0;
        const float4* g = (const float4*)(x + kbt * LBLK);
        float4 a = g[0], b = g[1];
        k[t][0] = a.x; k[t][1] = a.y; k[t][2] = a.z; k[t][3] = a.w;
        k[t][4] = b.x; k[t][5] = b.y; k[t][6] = b.z; k[t][7] = b.w;
        float q0 = a.x * a.x, q1 = a.y * a.y, q2 = a.z * a.z, q3 = a.w * a.w;
        float q4 = b.x * b.x, q5 = b.y * b.y, q6 = b.z * b.z, q7 = b.w * b.w;
        knorm[t] = ((q0 + q1) + (q2 + q3)) + ((q4 + q5) + (q6 + q7));
    }

    float best[TPK];
    int   gbs[TPK];
    const int rbase = wid * QROW;
    #pragma unroll
    for (int t = 0; t < TPK; ++t) { best[t] = 3.4e38f; gbs[t] = rbase; }

    const float4* sm4 = (const float4*)s_mem;

    // laundered global pointer: compiler can't prove uniformity -> emits
    // vector global_load (vmcnt pipe), NOT s_load (which shares lgkmcnt
    // with ds_read and would cross-serialize the two streams).
    const float4* gm4 = (const float4*)mem;
    asm volatile("" : "+v"(gm4));

    // the exact reference distance chain (bit-identical everywhere)
#define DIST(T, RA, RB, RN, DST)                                        \
    {                                                                   \
        float dot = k[(T)][0] * (RA).x;                                 \
        dot = fmaf(k[(T)][1], (RA).y, dot);                             \
        dot = fmaf(k[(T)][2], (RA).z, dot);                             \
        dot = fmaf(k[(T)][3], (RA).w, dot);                             \
        dot = fmaf(k[(T)][4], (RB).x, dot);                             \
        dot = fmaf(k[(T)][5], (RB).y, dot);                             \
        dot = fmaf(k[(T)][6], (RB).z, dot);                             \
        dot = fmaf(k[(T)][7], (RB).w, dot);                             \
        (DST) = fmaf(dot, -2.0f, knorm[(T)]) + (RN);                    \
    }

    // --- scan this wave's 64 rows: 16 windows of 4; rows 0-1 from LDS,
    //     rows 2-3 from global/L1 (same bytes, different pipe) ---
    #pragma unroll 1
    for (int w = 0; w < QROW; w += WIN) {
        const int r = rbase + w;
        float4 A0 = sm4[(r + 0) * 2 + 0], B0 = sm4[(r + 0) * 2 + 1];
        float4 A1 = sm4[(r + 1) * 2 + 0], B1 = sm4[(r + 1) * 2 + 1];
        float4 A2 = gm4[(r + 2) * 2 + 0], B2 = gm4[(r + 2) * 2 + 1];
        float4 A3 = gm4[(r + 3) * 2 + 0], B3 = gm4[(r + 3) * 2 + 1];
        float4 N  = *(const float4*)&s_norm[r];

        #pragma unroll
        for (int t = 0; t < TPK; ++t) {
            float d0, d1, d2, d3;
            DIST(t, A0, B0, N.x, d0);
            DIST(t, A1, B1, N.y, d1);
            DIST(t, A2, B2, N.z, d2);
            DIST(t, A3, B3, N.w, d3);
            // group min (order-independent value; all inputs finite)
            float gm = fminf(fminf(d0, d1), fminf(d2, d3));
            // strict < : FIRST group attaining this quarter's min wins
            if (gm < best[t]) { best[t] = gm; gbs[t] = r; }
        }
    }

    // --- publish: alias s_pub onto s_mem (dead after scan) ---
    __syncthreads();                 // all scan reads of s_mem complete
    unsigned long long* s_pub = (unsigned long long*)s_mem;   // [4][256]
    #pragma unroll
    for (int t = 0; t < TPK; ++t)
        s_pub[wid * 256 + t * 64 + lane] = packdi(best[t], gbs[t]);
    __syncthreads();

    // --- finalize: wave w owns keys t == w; u64-min over 4 quarters,
    //     resolve from global (L1-hot), store ---
#define FINALIZE(T)                                                     \
    {                                                                   \
        long b0 = (long)blockIdx.x * 256 + (T) * 64 + lane;             \
        if (b0 < (long)nblocks) {                                       \
            const int key = (T) * 64 + lane;                            \
            unsigned long long m0 = s_pub[0 * 256 + key];               \
            unsigned long long m1 = s_pub[1 * 256 + key];               \
            unsigned long long m2 = s_pub[2 * 256 + key];               \
            unsigned long long m3 = s_pub[3 * 256 + key];               \
            unsigned long long winv = m0 < m1 ? m0 : m1;                \
            winv = winv < m2 ? winv : m2;                               \
            winv = winv < m3 ? winv : m3;                               \
            unsigned int ob = (unsigned int)(winv >> 32);               \
            unsigned int bb = (ob & 0x80000000u) ? (ob ^ 0x80000000u)   \
                                                 : ~ob;                 \
            float fb = __uint_as_float(bb);                             \
            int   gb = (int)(winv & 0xffffffffu);                       \
            float4 wa = ((const float4*)(mem + (long)gb * LBLK))[0];    \
            float4 wb = ((const float4*)(mem + (long)gb * LBLK))[1];    \
            bool found = false;                                         \
            _Pragma("unroll")                                           \
            for (int j = 0; j < WIN; ++j) {                             \
                const float4* g =                                       \
                    (const float4*)(mem + (long)(gb + j) * LBLK);       \
                float4 a = g[0], b = g[1];                              \
                float q0 = a.x * a.x, q1 = a.y * a.y;                   \
                float q2 = a.z * a.z, q3 = a.w * a.w;                   \
                float q4 = b.x * b.x, q5 = b.y * b.y;                   \
                float q6 = b.z * b.z, q7 = b.w * b.w;                   \
                float nn = ((q0 + q1) + (q2 + q3))                      \
                         + ((q4 + q5) + (q6 + q7));                     \
                float d;                                                \
                DIST((T), a, b, nn, d);                                 \
                bool hit = (d == fb) && !found;                         \
                if (hit) { wa = a; wb = b; }                            \
                found = found || (d == fb);                             \
            }                                                           \
            float4* o = (float4*)(out + b0 * LBLK);                     \
            o[0] = wa;                                                  \
            o[1] = wb;                                                  \
        }                                                               \
    }

    if      (wid == 0) FINALIZE(0)
    else if (wid == 1) FINALIZE(1)
    else if (wid == 2) FINALIZE(2)
    else               FINALIZE(3)
#undef FINALIZE
#undef DIST
}

extern "C" void kernel_launch(void* const* d_in, const int* in_sizes, int n_in,
                              void* d_out, int out_size, void* d_ws, size_t ws_size,
                              hipStream_t stream) {
    const float* x   = (const float*)d_in[0];
    const float* mem = (const float*)d_in[1];
    float* out = (float*)d_out;

    int n = in_sizes[0];            // total x elements
    int nblocks = n / LBLK;         // key-blocks (802816 for std shape)
    int grid = (nblocks + 255) / 256;   // 3136 for std shape

    hipLaunchKernelGGL(crumb_kernel, dim3(grid), dim3(BLOCK), 0, stream,
                       x, mem, out, nblocks);
}

// Round 19
// 121.183 us; speedup vs baseline: 1.0189x; 1.0026x over previous
//
#include <hip/hip_runtime.h>

// CrumbReconstructor R21: R18's split granularity doubled — 8 waves x 32
// rows (same total DS reads and VALU work; finer burst alternation).
//
// R20 post-mortem: VMEM-split refuted (58.6 -> 65.3): uniform global_load
// pays per-window L1 latency, vmcnt wait uncovered. DS stays the row pipe.
//
// R18 state: real VALU-issue ~58% (derived 111-116 /2), = VALU-floor(34) /
// dur(58.6). The only lever that ever cut the 42% stall is granularity
// (R17 2-wave 65.3 -> R18 4-wave 58.6). R21 halves per-wave bursts again:
// QROW=32, 8 windows/wave (72 DS reads, ~2.8Kcy VALU), 25088 waves
// (98/CU over shifts; resident 32/CU = 4 blocks x 8 waves at VGPR<=64).
//
// Publish: separate [8][256] u64 (16KB; LDS 25.25KB -> still wave-capped
// at 4 blocks/CU, not LDS-capped). Merge = u64-min over 8 eighths; waves
// 0-3 finalize key-groups 0-3, waves 4-7 exit (tail cost trivial).
//
// Exactness (absmax must stay 0.0): DIST chain verbatim (mul, 7x fmaf,
// fmaf(dot,-2,knorm), +rn); within-eighth strict < keeps FIRST group of
// that eighth's min; u64 pack (orderedbits(dist)<<32 | gbase) min over 8
// eighths -> smallest distance, tie -> smallest gbase = earliest index
// (orderedbits monotone+bijective over finite floats); resolve recomputes
// the winning group's 4 distances from global (L1-hot) with the identical
// op tree and takes the FIRST d == best -> exact reference argmin.

#define LBLK 8          // memblock length
#define NROW 256        // codebook rows
#define QROW 32         // rows per wave (eighth of the row space)
#define BLOCK 512       // 8 waves per block
#define TPK 4           // key-groups; block covers 256 keys
#define WIN 4           // rows per window / argmin group
#define NWAVE 8

__device__ __forceinline__ unsigned long long packdi(float d, int g) {
    unsigned int b  = __float_as_uint(d);
    unsigned int ob = (b >> 31) ? ~b : (b | 0x80000000u);   // total order
    return ((unsigned long long)ob << 32) | (unsigned int)g;
}

__global__ __launch_bounds__(BLOCK, 4) void crumb_kernel(
    const float* __restrict__ x,
    const float* __restrict__ mem,
    float* __restrict__ out,
    int nblocks)
{
    __shared__ __align__(16) float s_mem[NROW * LBLK];    // 8 KB
    __shared__ __align__(16) float s_norm[NROW];          // 1 KB
    __shared__ unsigned long long s_pub[NWAVE * 256];     // 16 KB

    const int tid  = threadIdx.x;
    const int lane = tid & 63;
    const int wid  = tid >> 6;          // wave w scans rows [w*32, w*32+32)

    // --- stage codebook: threads 0..255 stage one row each ---
    if (tid < NROW) {
        const float4* g = (const float4*)mem;
        float4 a = g[tid * 2 + 0];
        float4 b = g[tid * 2 + 1];
        ((float4*)s_mem)[tid * 2 + 0] = a;
        ((float4*)s_mem)[tid * 2 + 1] = b;
        float q0 = a.x * a.x, q1 = a.y * a.y, q2 = a.z * a.z, q3 = a.w * a.w;
        float q4 = b.x * b.x, q5 = b.y * b.y, q6 = b.z * b.z, q7 = b.w * b.w;
        s_norm[tid] = ((q0 + q1) + (q2 + q3)) + ((q4 + q5) + (q6 + q7));
    }
    __syncthreads();

    // --- load the block's 256 keys (all 8 waves load the same keys) ---
    float k[TPK][LBLK];
    float knorm[TPK];

    #pragma unroll
    for (int t = 0; t < TPK; ++t) {
        long b0 = (long)blockIdx.x * 256 + t * 64 + lane;
        long kbt = (b0 < (long)nblocks) ? b0 : 0;
        const float4* g = (const float4*)(x + kbt * LBLK);
        float4 a = g[0], b = g[1];
        k[t][0] = a.x; k[t][1] = a.y; k[t][2] = a.z; k[t][3] = a.w;
        k[t][4] = b.x; k[t][5] = b.y; k[t][6] = b.z; k[t][7] = b.w;
        float q0 = a.x * a.x, q1 = a.y * a.y, q2 = a.z * a.z, q3 = a.w * a.w;
        float q4 = b.x * b.x, q5 = b.y * b.y, q6 = b.z * b.z, q7 = b.w * b.w;
        knorm[t] = ((q0 + q1) + (q2 + q3)) + ((q4 + q5) + (q6 + q7));
    }

    float best[TPK];
    int   gbs[TPK];
    const int rbase = wid * QROW;
    #pragma unroll
    for (int t = 0; t < TPK; ++t) { best[t] = 3.4e38f; gbs[t] = rbase; }

    const float4* sm4 = (const float4*)s_mem;

    // the exact reference distance chain (bit-identical everywhere)
#define DIST(T, RA, RB, RN, DST)                                        \
    {                                                                   \
        float dot = k[(T)][0] * (RA).x;                                 \
        dot = fmaf(k[(T)][1], (RA).y, dot);                             \
        dot = fmaf(k[(T)][2], (RA).z, dot);                             \
        dot = fmaf(k[(T)][3], (RA).w, dot);                             \
        dot = fmaf(k[(T)][4], (RB).x, dot);                             \
        dot = fmaf(k[(T)][5], (RB).y, dot);                             \
        dot = fmaf(k[(T)][6], (RB).z, dot);                             \
        dot = fmaf(k[(T)][7], (RB).w, dot);                             \
        (DST) = fmaf(dot, -2.0f, knorm[(T)]) + (RN);                    \
    }

    // --- scan this wave's 32 rows: 8 windows of 4 (proven body) ---
    #pragma unroll 1
    for (int w = 0; w < QROW; w += WIN) {
        const int r = rbase + w;
        float4 A0 = sm4[(r + 0) * 2 + 0], B0 = sm4[(r + 0) * 2 + 1];
        float4 A1 = sm4[(r + 1) * 2 + 0], B1 = sm4[(r + 1) * 2 + 1];
        float4 A2 = sm4[(r + 2) * 2 + 0], B2 = sm4[(r + 2) * 2 + 1];
        float4 A3 = sm4[(r + 3) * 2 + 0], B3 = sm4[(r + 3) * 2 + 1];
        float4 N  = *(const float4*)&s_norm[r];

        #pragma unroll
        for (int t = 0; t < TPK; ++t) {
            float d0, d1, d2, d3;
            DIST(t, A0, B0, N.x, d0);
            DIST(t, A1, B1, N.y, d1);
            DIST(t, A2, B2, N.z, d2);
            DIST(t, A3, B3, N.w, d3);
            // group min (order-independent value; all inputs finite)
            float gm = fminf(fminf(d0, d1), fminf(d2, d3));
            // strict < : FIRST group attaining this eighth's min wins
            if (gm < best[t]) { best[t] = gm; gbs[t] = r; }
        }
    }

    // --- publish: per-wave per-key packed (dist, groupbase) ---
    #pragma unroll
    for (int t = 0; t < TPK; ++t)
        s_pub[wid * 256 + t * 64 + lane] = packdi(best[t], gbs[t]);
    __syncthreads();

    // --- finalize: waves 0-3 own key-groups 0-3; u64-min over 8 eighths,
    //     resolve from global (L1-hot), store ---
#define FINALIZE(T)                                                     \
    {                                                                   \
        long b0 = (long)blockIdx.x * 256 + (T) * 64 + lane;             \
        if (b0 < (long)nblocks) {                                       \
            const int key = (T) * 64 + lane;                            \
            unsigned long long winv = s_pub[key];                       \
            _Pragma("unroll")                                           \
            for (int q = 1; q < NWAVE; ++q) {                           \
                unsigned long long m = s_pub[q * 256 + key];            \
                winv = m < winv ? m : winv;                             \
            }                                                           \
            unsigned int ob = (unsigned int)(winv >> 32);               \
            unsigned int bb = (ob & 0x80000000u) ? (ob ^ 0x80000000u)   \
                                                 : ~ob;                 \
            float fb = __uint_as_float(bb);                             \
            int   gb = (int)(winv & 0xffffffffu);                       \
            float4 wa = ((const float4*)(mem + (long)gb * LBLK))[0];    \
            float4 wb = ((const float4*)(mem + (long)gb * LBLK))[1];    \
            bool found = false;                                         \
            _Pragma("unroll")                                           \
            for (int j = 0; j < WIN; ++j) {                             \
                const float4* g =                                       \
                    (const float4*)(mem + (long)(gb + j) * LBLK);       \
                float4 a = g[0], b = g[1];                              \
                float q0 = a.x * a.x, q1 = a.y * a.y;                   \
                float q2 = a.z * a.z, q3 = a.w * a.w;                   \
                float q4 = b.x * b.x, q5 = b.y * b.y;                   \
                float q6 = b.z * b.z, q7 = b.w * b.w;                   \
                float nn = ((q0 + q1) + (q2 + q3))                      \
                         + ((q4 + q5) + (q6 + q7));                     \
                float d;                                                \
                DIST((T), a, b, nn, d);                                 \
                bool hit = (d == fb) && !found;                         \
                if (hit) { wa = a; wb = b; }                            \
                found = found || (d == fb);                             \
            }                                                           \
            float4* o = (float4*)(out + b0 * LBLK);                     \
            o[0] = wa;                                                  \
            o[1] = wb;                                                  \
        }                                                               \
    }

    if      (wid == 0) FINALIZE(0)
    else if (wid == 1) FINALIZE(1)
    else if (wid == 2) FINALIZE(2)
    else if (wid == 3) FINALIZE(3)
    // waves 4-7: done
#undef FINALIZE
#undef DIST
}

extern "C" void kernel_launch(void* const* d_in, const int* in_sizes, int n_in,
                              void* d_out, int out_size, void* d_ws, size_t ws_size,
                              hipStream_t stream) {
    const float* x   = (const float*)d_in[0];
    const float* mem = (const float*)d_in[1];
    float* out = (float*)d_out;

    int n = in_sizes[0];            // total x elements
    int nblocks = n / LBLK;         // key-blocks (802816 for std shape)
    int grid = (nblocks + 255) / 256;   // 3136 for std shape

    hipLaunchKernelGGL(crumb_kernel, dim3(grid), dim3(BLOCK), 0, stream,
                       x, mem, out, nblocks);
}

// Round 20
// 117.993 us; speedup vs baseline: 1.0464x; 1.0270x over previous
//
#include <hip/hip_runtime.h>

// CrumbReconstructor R22 = R18 verbatim (revert from R21; champion 58.6us).
//
// R21 post-mortem: granularity curve turned over (2w 65.3 -> 4w 58.6 ->
// 8w ~61): per-wave bursts too short to amortize redundant key loads,
// deeper publish/merge, and 512-thread barriers. 4 waves x 64 rows is the
// optimum of the last open axis.
//
// Final map (20 rounds): VALU issue floor ~34us; R18 = 58.6 = 58% issue
// efficiency. Closed axes: TPK {2,3,4,6}; split {1,2,4,8} waves; SMEM
// stream (89); VMEM/L1 rows (65); readlane (107); packed f32 (half-rate);
// sched_barrier pinning (-8%); src-level pipelining (discarded by
// scheduler); register shaping (AGPR parking benign, uncontrollable).
// Remaining stall = DS-broadcast delivery interleaved with a fixed VALU
// stream at ~3-4 schedulable waves/SIMD — structural at HIP level.
//
// Exactness (absmax 0.0, verified rounds 16): DIST chain (mul, 7x fmaf,
// fmaf(dot,-2,knorm), +rn); within-quarter strict < keeps FIRST group of
// that quarter's min; u64 pack (orderedbits(dist)<<32 | gbase) min over 4
// quarters -> smallest distance, tie -> smallest gbase = earliest index;
// resolve recomputes the winning group's 4 distances from global (L1-hot)
// with the identical op tree and takes the FIRST d == best.

#define LBLK 8          // memblock length
#define NROW 256        // codebook rows
#define QROW 64         // rows per wave (quarter of the row space)
#define BLOCK 256       // 4 waves per block
#define TPK 4           // keys per thread; block covers 256 keys
#define WIN 4           // rows per window / argmin group

__device__ __forceinline__ unsigned long long packdi(float d, int g) {
    unsigned int b  = __float_as_uint(d);
    unsigned int ob = (b >> 31) ? ~b : (b | 0x80000000u);   // total order
    return ((unsigned long long)ob << 32) | (unsigned int)g;
}

__global__ __launch_bounds__(BLOCK, 4) void crumb_kernel(
    const float* __restrict__ x,
    const float* __restrict__ mem,
    float* __restrict__ out,
    int nblocks)
{
    __shared__ __align__(16) float s_mem[NROW * LBLK];   // 8 KB; publish alias
    __shared__ __align__(16) float s_norm[NROW];         // 1 KB

    const int tid  = threadIdx.x;
    const int lane = tid & 63;
    const int wid  = tid >> 6;          // wave w scans rows [w*64, w*64+64)

    // --- stage codebook: 1 row per thread, coalesced ---
    {
        const float4* g = (const float4*)mem;
        float4 a = g[tid * 2 + 0];
        float4 b = g[tid * 2 + 1];
        ((float4*)s_mem)[tid * 2 + 0] = a;
        ((float4*)s_mem)[tid * 2 + 1] = b;
        float q0 = a.x * a.x, q1 = a.y * a.y, q2 = a.z * a.z, q3 = a.w * a.w;
        float q4 = b.x * b.x, q5 = b.y * b.y, q6 = b.z * b.z, q7 = b.w * b.w;
        s_norm[tid] = ((q0 + q1) + (q2 + q3)) + ((q4 + q5) + (q6 + q7));
    }
    __syncthreads();

    // --- load the block's 256 keys (all 4 waves load the same keys) ---
    float k[TPK][LBLK];
    float knorm[TPK];

    #pragma unroll
    for (int t = 0; t < TPK; ++t) {
        long b0 = (long)blockIdx.x * 256 + t * 64 + lane;
        long kbt = (b0 < (long)nblocks) ? b0 : 0;
        const float4* g = (const float4*)(x + kbt * LBLK);
        float4 a = g[0], b = g[1];
        k[t][0] = a.x; k[t][1] = a.y; k[t][2] = a.z; k[t][3] = a.w;
        k[t][4] = b.x; k[t][5] = b.y; k[t][6] = b.z; k[t][7] = b.w;
        float q0 = a.x * a.x, q1 = a.y * a.y, q2 = a.z * a.z, q3 = a.w * a.w;
        float q4 = b.x * b.x, q5 = b.y * b.y, q6 = b.z * b.z, q7 = b.w * b.w;
        knorm[t] = ((q0 + q1) + (q2 + q3)) + ((q4 + q5) + (q6 + q7));
    }

    float best[TPK];
    int   gbs[TPK];
    const int rbase = wid * QROW;
    #pragma unroll
    for (int t = 0; t < TPK; ++t) { best[t] = 3.4e38f; gbs[t] = rbase; }

    const float4* sm4 = (const float4*)s_mem;

    // the exact reference distance chain (bit-identical everywhere)
#define DIST(T, RA, RB, RN, DST)                                        \
    {                                                                   \
        float dot = k[(T)][0] * (RA).x;                                 \
        dot = fmaf(k[(T)][1], (RA).y, dot);                             \
        dot = fmaf(k[(T)][2], (RA).z, dot);                             \
        dot = fmaf(k[(T)][3], (RA).w, dot);                             \
        dot = fmaf(k[(T)][4], (RB).x, dot);                             \
        dot = fmaf(k[(T)][5], (RB).y, dot);                             \
        dot = fmaf(k[(T)][6], (RB).z, dot);                             \
        dot = fmaf(k[(T)][7], (RB).w, dot);                             \
        (DST) = fmaf(dot, -2.0f, knorm[(T)]) + (RN);                    \
    }

    // --- scan this wave's 64 rows: 16 windows of 4 (proven body) ---
    #pragma unroll 1
    for (int w = 0; w < QROW; w += WIN) {
        const int r = rbase + w;
        float4 A0 = sm4[(r + 0) * 2 + 0], B0 = sm4[(r + 0) * 2 + 1];
        float4 A1 = sm4[(r + 1) * 2 + 0], B1 = sm4[(r + 1) * 2 + 1];
        float4 A2 = sm4[(r + 2) * 2 + 0], B2 = sm4[(r + 2) * 2 + 1];
        float4 A3 = sm4[(r + 3) * 2 + 0], B3 = sm4[(r + 3) * 2 + 1];
        float4 N  = *(const float4*)&s_norm[r];

        #pragma unroll
        for (int t = 0; t < TPK; ++t) {
            float d0, d1, d2, d3;
            DIST(t, A0, B0, N.x, d0);
            DIST(t, A1, B1, N.y, d1);
            DIST(t, A2, B2, N.z, d2);
            DIST(t, A3, B3, N.w, d3);
            // group min (order-independent value; all inputs finite)
            float gm = fminf(fminf(d0, d1), fminf(d2, d3));
            // strict < : FIRST group attaining this quarter's min wins
            if (gm < best[t]) { best[t] = gm; gbs[t] = r; }
        }
    }

    // --- publish: alias s_pub onto s_mem (dead after scan) ---
    __syncthreads();                 // all scan reads of s_mem complete
    unsigned long long* s_pub = (unsigned long long*)s_mem;   // [4][256]
    #pragma unroll
    for (int t = 0; t < TPK; ++t)
        s_pub[wid * 256 + t * 64 + lane] = packdi(best[t], gbs[t]);
    __syncthreads();

    // --- finalize: wave w owns keys t == w; u64-min over 4 quarters,
    //     resolve from global (L1-hot), store ---
#define FINALIZE(T)                                                     \
    {                                                                   \
        long b0 = (long)blockIdx.x * 256 + (T) * 64 + lane;             \
        if (b0 < (long)nblocks) {                                       \
            const int key = (T) * 64 + lane;                            \
            unsigned long long m0 = s_pub[0 * 256 + key];               \
            unsigned long long m1 = s_pub[1 * 256 + key];               \
            unsigned long long m2 = s_pub[2 * 256 + key];               \
            unsigned long long m3 = s_pub[3 * 256 + key];               \
            unsigned long long winv = m0 < m1 ? m0 : m1;                \
            winv = winv < m2 ? winv : m2;                               \
            winv = winv < m3 ? winv : m3;                               \
            unsigned int ob = (unsigned int)(winv >> 32);               \
            unsigned int bb = (ob & 0x80000000u) ? (ob ^ 0x80000000u)   \
                                                 : ~ob;                 \
            float fb = __uint_as_float(bb);                             \
            int   gb = (int)(winv & 0xffffffffu);                       \
            float4 wa = ((const float4*)(mem + (long)gb * LBLK))[0];    \
            float4 wb = ((const float4*)(mem + (long)gb * LBLK))[1];    \
            bool found = false;                                         \
            _Pragma("unroll")                                           \
            for (int j = 0; j < WIN; ++j) {                             \
                const float4* g =                                       \
                    (const float4*)(mem + (long)(gb + j) * LBLK);       \
                float4 a = g[0], b = g[1];                              \
                float q0 = a.x * a.x, q1 = a.y * a.y;                   \
                float q2 = a.z * a.z, q3 = a.w * a.w;                   \
                float q4 = b.x * b.x, q5 = b.y * b.y;                   \
                float q6 = b.z * b.z, q7 = b.w * b.w;                   \
                float nn = ((q0 + q1) + (q2 + q3))                      \
                         + ((q4 + q5) + (q6 + q7));                     \
                float d;                                                \
                DIST((T), a, b, nn, d);                                 \
                bool hit = (d == fb) && !found;                         \
                if (hit) { wa = a; wb = b; }                            \
                found = found || (d == fb);                             \
            }                                                           \
            float4* o = (float4*)(out + b0 * LBLK);                     \
            o[0] = wa;                                                  \
            o[1] = wb;                                                  \
        }                                                               \
    }

    if      (wid == 0) FINALIZE(0)
    else if (wid == 1) FINALIZE(1)
    else if (wid == 2) FINALIZE(2)
    else               FINALIZE(3)
#undef FINALIZE
#undef DIST
}

extern "C" void kernel_launch(void* const* d_in, const int* in_sizes, int n_in,
                              void* d_out, int out_size, void* d_ws, size_t ws_size,
                              hipStream_t stream) {
    const float* x   = (const float*)d_in[0];
    const float* mem = (const float*)d_in[1];
    float* out = (float*)d_out;

    int n = in_sizes[0];            // total x elements
    int nblocks = n / LBLK;         // key-blocks (802816 for std shape)
    int grid = (nblocks + 255) / 256;   // 3136 for std shape

    hipLaunchKernelGGL(crumb_kernel, dim3(grid), dim3(BLOCK), 0, stream,
                       x, mem, out, nblocks);
}